// Round 3
// baseline (429.580 us; speedup 1.0000x reference)
//
#include <hip/hip_runtime.h>
#include <hip/hip_fp16.h>
#include <cmath>

// ButterflyRotation: 12 layers of stride-2^l Givens rotations on rows of 4096 fp32.
// R5 (resubmit — previous round hit a GPU-acquisition timeout, never measured):
// persistent blocks (grid 2048, 4 rows each) with next-row register prefetch
// issued ~1500 cycles before use, so the ~900-cycle HBM load latency is off the
// critical path. Angle loads for each phase issued before the preceding barrier.
// LDS pad addressing hand-reduced to base + compile-time offsets (pad is affine
// per phase). 3 barriers/row. VGPR budget ~60: v[16]+pv[16]+ang[16].

namespace {
constexpr int kDim = 4096;
constexpr int kBatch = 8192;
constexpr int kLayers = 12;
constexpr int kPairs = kDim / 2;            // 2048
constexpr int kThreads = 256;
constexpr int kRowsPerBlock = 4;
// Pad 4 words per 64: strided phase accesses stay <=2-way bank aliased (free
// per m136) and 16B alignment is preserved for b128 writes.
constexpr int kLdsWords = kDim + 4 * (kDim / 64);  // 4352 words = 17408 B
}

__device__ __forceinline__ int lds_pad(int i) { return i + ((i >> 6) << 2); }

// slot (l, t, q) -> original pair index p, shared by precompute + main kernel.
__device__ __forceinline__ int slot_to_pair(int l, int t, int q) {
    const int m = l & 3;
    const int phase = l >> 2;
    const int j = ((q >> m) << (m + 1)) | (q & ((1 << m) - 1));  // local left idx
    int i;
    if (phase == 0)      i = 16 * t + j;                          // strides 1..8
    else if (phase == 1) i = (t & 15) + 16 * j + 256 * (t >> 4);  // strides 16..128
    else                 i = t + 256 * j;                         // strides 256..2048
    const int s = 1 << l;
    return ((i >> (l + 1)) << l) | (i & (s - 1));                 // global pair idx
}

// Precompute permuted sin(angle) as fp16, one per (layer, slot). 48 KiB total.
__global__ void bf_precompute_s(const float* __restrict__ angles,
                                __half* __restrict__ sperm) {
    const int k = blockIdx.x * blockDim.x + threadIdx.x;
    if (k >= kLayers * kPairs) return;
    const int l = k >> 11;          // / 2048
    const int slot = k & 2047;
    const int t = slot >> 3;
    const int q = slot & 7;
    const int p = slot_to_pair(l, t, q);
    sperm[k] = __float2half(sinf(angles[l * kPairs + p]));
}

// Apply 4 layers (m = 0..3 within a phase) given their packed sin halves.
__device__ __forceinline__ void apply_phase(float (&v)[16], const uint4 (&ang)[4]) {
#pragma unroll
    for (int m = 0; m < 4; ++m) {
        __half h[8];
        *reinterpret_cast<uint4*>(h) = ang[m];
#pragma unroll
        for (int q = 0; q < 8; ++q) {
            const int j = ((q >> m) << (m + 1)) | (q & ((1 << m) - 1));
            const int jp = j + (1 << m);
            const float s = __half2float(h[q]);
            const float t2 = s * s;
            const float cm1 = -t2 * fmaf(0.125f, t2, 0.5f);  // cos(a) - 1, |err|~2e-10
            const float xl = v[j], xr = v[jp];
            // new_left  = xl*c + xr*s = xl + xl*cm1 + xr*s
            // new_right = xr*c - xl*s = xr + xr*cm1 - xl*s
            v[j]  = fmaf(xl, cm1, fmaf(xr,  s, xl));
            v[jp] = fmaf(xr, cm1, fmaf(-xl, s, xr));
        }
    }
}

__global__ __launch_bounds__(kThreads, 6)
void bf_butterfly(const float* __restrict__ x,
                  const __half* __restrict__ sperm,
                  float* __restrict__ out) {
    __shared__ float lds[kLdsWords];
    const int t = threadIdx.x;
    const int low = t & 15, high = t >> 4;
    // Hand-reduced padded addresses (pad term is affine per access pattern):
    //   exchange-A write: lds_pad(16t+4k)          = baseA + 4k
    //   phase-1 r/w:      lds_pad(low+16j+256high) = base1 + 16j + 4*(j>>2)
    //   phase-2 read:     lds_pad(t+256j)          = base2 + 272j
    const int baseA = 16 * t + 4 * (t >> 2);
    const int base1 = low + 272 * high;
    const int base2 = t + 4 * (t >> 6);
    const uint4* ap = reinterpret_cast<const uint4*>(sperm);

    const int row0 = blockIdx.x * kRowsPerBlock;

    // phase-0 angles for the first row
    uint4 ang[4];
#pragma unroll
    for (int m = 0; m < 4; ++m) ang[m] = ap[m * 256 + t];

    // load row0: thread t owns contiguous elements [16t, 16t+16)
    float v[16], pv[16];
    {
        const float4* src = reinterpret_cast<const float4*>(x + (size_t)row0 * kDim + 16 * t);
#pragma unroll
        for (int k = 0; k < 4; ++k) {
            const float4 f = src[k];
            v[4 * k + 0] = f.x; v[4 * k + 1] = f.y;
            v[4 * k + 2] = f.z; v[4 * k + 3] = f.w;
        }
    }

#pragma unroll
    for (int r = 0; r < kRowsPerBlock; ++r) {
        const int row = row0 + r;

        // ---- phase 0: strides 1..8, in registers ----
        apply_phase(v, ang);

        __syncthreads();  // X: previous row's phase-2 LDS reads complete

        // ---- exchange A write: contiguous-16 layout ----
#pragma unroll
        for (int k = 0; k < 4; ++k) {
            *reinterpret_cast<float4*>(&lds[baseA + 4 * k]) =
                make_float4(v[4 * k], v[4 * k + 1], v[4 * k + 2], v[4 * k + 3]);
        }

        // ---- prefetch NEXT row now; consumed after 2 barriers + 2 phases ----
        if (r + 1 < kRowsPerBlock) {
            const float4* nsrc = reinterpret_cast<const float4*>(
                x + (size_t)(row + 1) * kDim + 16 * t);
#pragma unroll
            for (int k = 0; k < 4; ++k) {
                const float4 f = nsrc[k];
                pv[4 * k + 0] = f.x; pv[4 * k + 1] = f.y;
                pv[4 * k + 2] = f.z; pv[4 * k + 3] = f.w;
            }
        }

        // phase-1 angles (global, independent of LDS) before the barrier
#pragma unroll
        for (int m = 0; m < 4; ++m) ang[m] = ap[(4 + m) * 256 + t];

        __syncthreads();  // Y: exchange-A visible
#pragma unroll
        for (int j = 0; j < 16; ++j) {
            v[j] = lds[base1 + 16 * j + 4 * (j >> 2)];
        }

        // ---- phase 1: strides 16..128 ----
        apply_phase(v, ang);

        // exchange B write: SAME addresses this thread just read -> WAR is
        // intra-thread only, no barrier needed before the writes.
#pragma unroll
        for (int j = 0; j < 16; ++j) {
            lds[base1 + 16 * j + 4 * (j >> 2)] = v[j];
        }

        // phase-2 angles before the barrier
#pragma unroll
        for (int m = 0; m < 4; ++m) ang[m] = ap[(8 + m) * 256 + t];

        __syncthreads();  // Z: exchange-B visible
#pragma unroll
        for (int j = 0; j < 16; ++j) {
            v[j] = lds[base2 + 272 * j];
        }

        // ---- phase 2: strides 256..2048 ----
        apply_phase(v, ang);

        // next row's phase-0 angles (ang regs dead after the apply above);
        // hidden behind the 16 stores + barrier X.
        if (r + 1 < kRowsPerBlock) {
#pragma unroll
            for (int m = 0; m < 4; ++m) ang[m] = ap[m * 256 + t];
        }

        // ---- store: coalesced (lane t writes element t + 256j), nontemporal ----
        float* dst = out + (size_t)row * kDim;
#pragma unroll
        for (int j = 0; j < 16; ++j) {
            __builtin_nontemporal_store(v[j], dst + t + 256 * j);
        }

        if (r + 1 < kRowsPerBlock) {
#pragma unroll
            for (int j = 0; j < 16; ++j) v[j] = pv[j];
        }
    }
}

extern "C" void kernel_launch(void* const* d_in, const int* in_sizes, int n_in,
                              void* d_out, int out_size, void* d_ws, size_t ws_size,
                              hipStream_t stream) {
    (void)in_sizes; (void)n_in; (void)out_size; (void)ws_size;
    const float* x = (const float*)d_in[0];
    const float* angles = (const float*)d_in[1];
    // d_in[2]/d_in[3] (left_idx/right_idx) are recomputed analytically.
    __half* sperm = (__half*)d_ws;  // 12*2048 fp16 = 48 KiB
    float* out = (float*)d_out;

    bf_precompute_s<<<(kLayers * kPairs + kThreads - 1) / kThreads, kThreads, 0, stream>>>(
        angles, sperm);
    bf_butterfly<<<kBatch / kRowsPerBlock, kThreads, 0, stream>>>(x, sperm, out);
}

// Round 6
// 279.395 us; speedup vs baseline: 1.5375x; 1.5375x over previous
//
#include <hip/hip_runtime.h>
#include <hip/hip_fp16.h>
#include <cmath>

// ButterflyRotation: 12 layers of stride-2^l Givens rotations on rows of 4096 fp32.
// R6 (second resubmit — rounds 4 and 5 both hit GPU-acquisition timeouts; never
// measured): revert R5's spilled persistent/prefetch scheme (WRITE_SIZE 3x =
// scratch; vmcnt(0) drains at every barrier make pre-barrier prefetch void).
// Structure is R4's proven 2-barrier single-shot, plus:
//  - 2 rows per thread as float2 lane pairs: angle values + all addressing
//    amortized over 2 rows (per-row VALU overhead ~halved).
//  - fp32 (sin, cos-1) table (192 KB, L2-resident): rotation = 8 FMAs for 2 rows,
//    zero cvt/unpack/series math.
//  - all VMEM issued only at kernel start or after barriers (never pending at one).

namespace {
constexpr int kDim = 4096;
constexpr int kBatch = 8192;
constexpr int kLayers = 12;
constexpr int kPairs = kDim / 2;            // 2048
constexpr int kThreads = 256;
constexpr int kRowsPerBlock = 2;            // processed together, float2 per lane
// Pad 4 words per 64: strided phase accesses stay <=2-way bank aliased (free
// per m136) and 16B alignment is preserved for b128 writes.
constexpr int kPlaneWords = kDim + 4 * (kDim / 64);  // 4352 words = 17408 B/plane
}

// slot (l, t, q) -> original pair index p, shared by precompute + main kernel.
__device__ __forceinline__ int slot_to_pair(int l, int t, int q) {
    const int m = l & 3;
    const int phase = l >> 2;
    const int j = ((q >> m) << (m + 1)) | (q & ((1 << m) - 1));  // local left idx
    int i;
    if (phase == 0)      i = 16 * t + j;                          // strides 1..8
    else if (phase == 1) i = (t & 15) + 16 * j + 256 * (t >> 4);  // strides 16..128
    else                 i = t + 256 * j;                         // strides 256..2048
    const int s = 1 << l;
    return ((i >> (l + 1)) << l) | (i & (s - 1));                 // global pair idx
}

// Precompute permuted (sin, cos-1) as fp32, one float2 per (layer, slot). 192 KiB.
__global__ void bf_precompute(const float* __restrict__ angles,
                              float2* __restrict__ tab) {
    const int k = blockIdx.x * blockDim.x + threadIdx.x;
    if (k >= kLayers * kPairs) return;
    const int l = k >> 11;          // / 2048
    const int slot = k & 2047;
    const int t = slot >> 3;
    const int q = slot & 7;
    const int p = slot_to_pair(l, t, q);
    const float a = angles[l * kPairs + p];
    tab[k] = make_float2(sinf(a), cosf(a) - 1.0f);
}

// Apply 4 layers (m = 0..3 within a phase); v[j] holds (row0, row1) element pair.
template <int PHASE>
__device__ __forceinline__ void apply_phase(float2 (&v)[16],
                                            const float2* __restrict__ tab,
                                            int t) {
#pragma unroll
    for (int m = 0; m < 4; ++m) {
        const int l = PHASE * 4 + m;
        // 8 slots (s, cm1) for this (layer, thread): 32 B contiguous, 2 x float4.
        const float4* tp =
            reinterpret_cast<const float4*>(tab + ((size_t)l * kPairs + 8 * t));
        float2 sc[8];
#pragma unroll
        for (int k = 0; k < 4; ++k) {
            const float4 f = tp[k];
            sc[2 * k + 0] = make_float2(f.x, f.y);
            sc[2 * k + 1] = make_float2(f.z, f.w);
        }
#pragma unroll
        for (int q = 0; q < 8; ++q) {
            const int j = ((q >> m) << (m + 1)) | (q & ((1 << m) - 1));
            const int jp = j + (1 << m);
            const float s = sc[q].x, cm1 = sc[q].y;
            const float2 xl = v[j], xr = v[jp];
            // new_left  = xl + xl*cm1 + xr*s ; new_right = xr + xr*cm1 - xl*s
            v[j].x  = fmaf(xl.x, cm1, fmaf(xr.x,  s, xl.x));
            v[j].y  = fmaf(xl.y, cm1, fmaf(xr.y,  s, xl.y));
            v[jp].x = fmaf(xr.x, cm1, fmaf(-xl.x, s, xr.x));
            v[jp].y = fmaf(xr.y, cm1, fmaf(-xl.y, s, xr.y));
        }
    }
}

__global__ __launch_bounds__(kThreads, 4)
void bf_butterfly(const float* __restrict__ x,
                  const float2* __restrict__ tab,
                  float* __restrict__ out) {
    __shared__ float lds[2 * kPlaneWords];   // plane per row, 34816 B
    const int t = threadIdx.x;
    const int low = t & 15, high = t >> 4;
    // Hand-reduced padded addresses (pad term is affine per access pattern):
    //   exchange-A write: lds_pad(16t+4k)          = baseA + 4k
    //   phase-1 r/w:      lds_pad(low+16j+256high) = base1 + 16j + 4*(j>>2)
    //   phase-2 read:     lds_pad(t+256j)          = base2 + 272j
    const int baseA = 16 * t + 4 * (t >> 2);
    const int base1 = low + 272 * high;
    const int base2 = t + 4 * (t >> 6);

    const int r0 = blockIdx.x * kRowsPerBlock;

    // ---- load both rows: thread t owns contiguous elements [16t, 16t+16) ----
    float2 v[16];
    {
        const float4* s0 = reinterpret_cast<const float4*>(x + (size_t)r0 * kDim + 16 * t);
        const float4* s1 = reinterpret_cast<const float4*>(x + (size_t)(r0 + 1) * kDim + 16 * t);
        float4 a0[4], a1[4];
#pragma unroll
        for (int k = 0; k < 4; ++k) { a0[k] = s0[k]; a1[k] = s1[k]; }
#pragma unroll
        for (int k = 0; k < 4; ++k) {
            v[4 * k + 0] = make_float2(a0[k].x, a1[k].x);
            v[4 * k + 1] = make_float2(a0[k].y, a1[k].y);
            v[4 * k + 2] = make_float2(a0[k].z, a1[k].z);
            v[4 * k + 3] = make_float2(a0[k].w, a1[k].w);
        }
    }

    // ---- phase 0: strides 1..8, in registers ----
    apply_phase<0>(v, tab, t);

    // ---- exchange A write: contiguous-16 layout, planar per row ----
#pragma unroll
    for (int k = 0; k < 4; ++k) {
        *reinterpret_cast<float4*>(&lds[baseA + 4 * k]) =
            make_float4(v[4 * k].x, v[4 * k + 1].x, v[4 * k + 2].x, v[4 * k + 3].x);
        *reinterpret_cast<float4*>(&lds[kPlaneWords + baseA + 4 * k]) =
            make_float4(v[4 * k].y, v[4 * k + 1].y, v[4 * k + 2].y, v[4 * k + 3].y);
    }
    __syncthreads();  // Y: exchange-A visible (no VMEM outstanding here)
#pragma unroll
    for (int j = 0; j < 16; ++j) {
        const int a = base1 + 16 * j + 4 * (j >> 2);
        v[j].x = lds[a];
        v[j].y = lds[kPlaneWords + a];
    }

    // ---- phase 1: strides 16..128 (angle loads issued after the barrier) ----
    apply_phase<1>(v, tab, t);

    // exchange B write: SAME addresses this thread just read -> WAR is
    // intra-thread only, no barrier needed before the writes.
#pragma unroll
    for (int j = 0; j < 16; ++j) {
        const int a = base1 + 16 * j + 4 * (j >> 2);
        lds[a] = v[j].x;
        lds[kPlaneWords + a] = v[j].y;
    }
    __syncthreads();  // Z: exchange-B visible
#pragma unroll
    for (int j = 0; j < 16; ++j) {
        const int a = base2 + 272 * j;
        v[j].x = lds[a];
        v[j].y = lds[kPlaneWords + a];
    }

    // ---- phase 2: strides 256..2048 ----
    apply_phase<2>(v, tab, t);

    // ---- store: coalesced (lane t writes element t + 256j), nontemporal ----
    float* d0 = out + (size_t)r0 * kDim;
    float* d1 = d0 + kDim;
#pragma unroll
    for (int j = 0; j < 16; ++j) {
        __builtin_nontemporal_store(v[j].x, d0 + t + 256 * j);
        __builtin_nontemporal_store(v[j].y, d1 + t + 256 * j);
    }
}

extern "C" void kernel_launch(void* const* d_in, const int* in_sizes, int n_in,
                              void* d_out, int out_size, void* d_ws, size_t ws_size,
                              hipStream_t stream) {
    (void)in_sizes; (void)n_in; (void)out_size; (void)ws_size;
    const float* x = (const float*)d_in[0];
    const float* angles = (const float*)d_in[1];
    // d_in[2]/d_in[3] (left_idx/right_idx) are recomputed analytically.
    float2* tab = (float2*)d_ws;  // 12*2048 float2 = 192 KiB
    float* out = (float*)d_out;

    bf_precompute<<<(kLayers * kPairs + kThreads - 1) / kThreads, kThreads, 0, stream>>>(
        angles, tab);
    bf_butterfly<<<kBatch / kRowsPerBlock, kThreads, 0, stream>>>(x, tab, out);
}

// Round 9
// 257.330 us; speedup vs baseline: 1.6694x; 1.0857x over previous
//
#include <hip/hip_runtime.h>
#include <hip/hip_fp16.h>
#include <cmath>

// ButterflyRotation: 12 layers of stride-2^l Givens rotations on rows of 4096 fp32.
// R7 (third submit — rounds 7 and 8 hit GPU-acquisition timeouts; never measured):
// R6 post-mortem — VALU cut worked (51%->16.7% busy) but concurrency collapsed
// (occ 38.5%, 4 blocks/CU from 34.8KB LDS; table loads moved post-barrier put L2
// latency on the critical path). R7 keeps R4's proven concurrency shape (1 row per
// block, 17.4KB LDS, 8192 blocks, phase-hoisted pre-barrier table loads — the
// vmcnt(0) drain at barriers COMPLETES them during the barrier wait, which is
// good, not void) and imports R6's math cut via a half2(sin, cos-1) table:
// per phase = 8 uint4 = 32 VGPRs hoistable; rotation = 2 cvt + 4 FMA.
// __launch_bounds__(256,8) pins VGPR <= 64 (the m69 occupancy cliff).

namespace {
constexpr int kDim = 4096;
constexpr int kBatch = 8192;
constexpr int kLayers = 12;
constexpr int kPairs = kDim / 2;            // 2048
constexpr int kThreads = 256;
// Pad 4 words per 64: strided phase accesses stay <=2-way bank aliased (free
// per m136) and 16B alignment is preserved for b128 writes.
constexpr int kLdsWords = kDim + 4 * (kDim / 64);  // 4352 words = 17408 B
}

__device__ __forceinline__ int lds_pad(int i) { return i + ((i >> 6) << 2); }

// slot (l, t, q) -> original pair index p, shared by precompute + main kernel.
__device__ __forceinline__ int slot_to_pair(int l, int t, int q) {
    const int m = l & 3;
    const int phase = l >> 2;
    const int j = ((q >> m) << (m + 1)) | (q & ((1 << m) - 1));  // local left idx
    int i;
    if (phase == 0)      i = 16 * t + j;                          // strides 1..8
    else if (phase == 1) i = (t & 15) + 16 * j + 256 * (t >> 4);  // strides 16..128
    else                 i = t + 256 * j;                         // strides 256..2048
    const int s = 1 << l;
    return ((i >> (l + 1)) << l) | (i & (s - 1));                 // global pair idx
}

// Precompute permuted half2(sin, cos-1), one per (layer, slot). 96 KiB total.
// cm1 in [-1.25e-3, 0] is fp16-normal; rel err 5e-4 -> abs err ~6e-7, negligible.
__global__ void bf_precompute(const float* __restrict__ angles,
                              __half2* __restrict__ tab) {
    const int k = blockIdx.x * blockDim.x + threadIdx.x;
    if (k >= kLayers * kPairs) return;
    const int l = k >> 11;          // / 2048
    const int slot = k & 2047;
    const int t = slot >> 3;
    const int q = slot & 7;
    const int p = slot_to_pair(l, t, q);
    const float a = angles[l * kPairs + p];
    tab[k] = __floats2half2_rn(sinf(a), cosf(a) - 1.0f);
}

// Apply 4 layers (m = 0..3 within a phase); tb = 8 uint4 (2 per layer) of half2
// (s, cm1) slots for this thread, loaded by the caller (pre-barrier).
__device__ __forceinline__ void apply_phase(float (&v)[16], const uint4 (&tb)[8]) {
#pragma unroll
    for (int m = 0; m < 4; ++m) {
        const __half2* h = reinterpret_cast<const __half2*>(&tb[2 * m]);
#pragma unroll
        for (int q = 0; q < 8; ++q) {
            const int j = ((q >> m) << (m + 1)) | (q & ((1 << m) - 1));
            const int jp = j + (1 << m);
            const float2 sc = __half22float2(h[q]);
            const float s = sc.x, cm1 = sc.y;
            const float xl = v[j], xr = v[jp];
            // new_left  = xl + xl*cm1 + xr*s ; new_right = xr + xr*cm1 - xl*s
            v[j]  = fmaf(xl, cm1, fmaf(xr,  s, xl));
            v[jp] = fmaf(xr, cm1, fmaf(-xl, s, xr));
        }
    }
}

__global__ __launch_bounds__(kThreads, 8)
void bf_butterfly(const float* __restrict__ x,
                  const __half2* __restrict__ tab,
                  float* __restrict__ out) {
    __shared__ float lds[kLdsWords];
    const int t = threadIdx.x;
    const int low = t & 15, high = t >> 4;
    // Hand-reduced padded addresses (pad term is affine per access pattern):
    //   exchange-A write: lds_pad(16t+4k)          = baseA + 4k
    //   phase-1 r/w:      lds_pad(low+16j+256high) = base1 + 16j + 4*(j>>2)
    //   phase-2 read:     lds_pad(t+256j)          = base2 + 272j
    const int baseA = 16 * t + 4 * (t >> 2);
    const int base1 = low + 272 * high;
    const int base2 = t + 4 * (t >> 6);
    const int row = blockIdx.x;

    // Table as uint4: layer l, thread t -> uint4 indices l*512 + 2t, l*512 + 2t+1.
    const uint4* ap = reinterpret_cast<const uint4*>(tab);

    // ---- phase-0 table: 8 uint4 = 32 VGPRs ----
    uint4 tb[8];
#pragma unroll
    for (int m = 0; m < 4; ++m) {
        tb[2 * m]     = ap[m * 512 + 2 * t];
        tb[2 * m + 1] = ap[m * 512 + 2 * t + 1];
    }

    // ---- load row: thread t owns contiguous elements [16t, 16t+16) ----
    float v[16];
    {
        const float4* src = reinterpret_cast<const float4*>(x + (size_t)row * kDim + 16 * t);
#pragma unroll
        for (int k = 0; k < 4; ++k) {
            const float4 f = src[k];
            v[4 * k + 0] = f.x; v[4 * k + 1] = f.y;
            v[4 * k + 2] = f.z; v[4 * k + 3] = f.w;
        }
    }

    // ---- phase 0: strides 1..8, in registers ----
    apply_phase(v, tb);

    // ---- exchange A write: contiguous-16 layout ----
#pragma unroll
    for (int k = 0; k < 4; ++k) {
        *reinterpret_cast<float4*>(&lds[baseA + 4 * k]) =
            make_float4(v[4 * k], v[4 * k + 1], v[4 * k + 2], v[4 * k + 3]);
    }

    // phase-1 table issued pre-barrier: completes during the barrier wait.
#pragma unroll
    for (int m = 0; m < 4; ++m) {
        tb[2 * m]     = ap[(4 + m) * 512 + 2 * t];
        tb[2 * m + 1] = ap[(4 + m) * 512 + 2 * t + 1];
    }

    __syncthreads();  // Y: exchange-A visible
#pragma unroll
    for (int j = 0; j < 16; ++j) {
        v[j] = lds[base1 + 16 * j + 4 * (j >> 2)];
    }

    // ---- phase 1: strides 16..128 ----
    apply_phase(v, tb);

    // exchange B write: SAME addresses this thread just read -> WAR is
    // intra-thread only, no barrier needed before the writes.
#pragma unroll
    for (int j = 0; j < 16; ++j) {
        lds[base1 + 16 * j + 4 * (j >> 2)] = v[j];
    }

    // phase-2 table issued pre-barrier.
#pragma unroll
    for (int m = 0; m < 4; ++m) {
        tb[2 * m]     = ap[(8 + m) * 512 + 2 * t];
        tb[2 * m + 1] = ap[(8 + m) * 512 + 2 * t + 1];
    }

    __syncthreads();  // Z: exchange-B visible
#pragma unroll
    for (int j = 0; j < 16; ++j) {
        v[j] = lds[base2 + 272 * j];
    }

    // ---- phase 2: strides 256..2048 ----
    apply_phase(v, tb);

    // ---- store: coalesced (lane t writes element t + 256j), nontemporal ----
    float* dst = out + (size_t)row * kDim;
#pragma unroll
    for (int j = 0; j < 16; ++j) {
        __builtin_nontemporal_store(v[j], dst + t + 256 * j);
    }
}

extern "C" void kernel_launch(void* const* d_in, const int* in_sizes, int n_in,
                              void* d_out, int out_size, void* d_ws, size_t ws_size,
                              hipStream_t stream) {
    (void)in_sizes; (void)n_in; (void)out_size; (void)ws_size;
    const float* x = (const float*)d_in[0];
    const float* angles = (const float*)d_in[1];
    // d_in[2]/d_in[3] (left_idx/right_idx) are recomputed analytically.
    __half2* tab = (__half2*)d_ws;  // 12*2048 half2 = 96 KiB
    float* out = (float*)d_out;

    bf_precompute<<<(kLayers * kPairs + kThreads - 1) / kThreads, kThreads, 0, stream>>>(
        angles, tab);
    bf_butterfly<<<kBatch, kThreads, 0, stream>>>(x, tab, out);
}